// Round 1
// baseline (1166.088 us; speedup 1.0000x reference)
//
#include <hip/hip_runtime.h>

// ShiftedWindowAttention on MI355X (gfx950), bf16 MFMA implementation.
// B=16, H=W=112, C=256, NH=8, hd=32, window 7x7 (N=49), shift 3, nWin=4096.
// Workspace layout (bf16 elems unless noted):
//   qws [4096*49][256] | kws [...] | vws [...] | wbf [4][256][256] | bias f32 [8][49][49]
// needs ~309 MB of d_ws.

typedef short  bf16x8_t __attribute__((ext_vector_type(8)));
typedef float  f32x4_t  __attribute__((ext_vector_type(4)));
typedef int    i32x4_t  __attribute__((ext_vector_type(4)));

#define HH    112
#define WWDIM 112
#define NTOK  49
#define NWIN  4096
#define SHIFT 3

__device__ __forceinline__ unsigned short f2bf(float f) {
  unsigned u = __builtin_bit_cast(unsigned, f);
  u += 0x7FFFu + ((u >> 16) & 1u);           // RNE
  return (unsigned short)(u >> 16);
}

__device__ __forceinline__ bf16x8_t ld8(const unsigned short* p) {
  return __builtin_bit_cast(bf16x8_t, *reinterpret_cast<const i32x4_t*>(p));
}

// XOR-swizzled index (ushort units) shared by writer+reader. rowElems = bf16/row.
__device__ __forceinline__ int swzi(int row, int col, int rowElems) {
  int by = col << 1;
  int sb = (((by >> 4) ^ (row & 7)) << 4) | (by & 15);
  return row * rowElems + (sb >> 1);
}

// ---------------- prep: weights -> bf16, bias table ----------------
__global__ void prep_kernel(const float* __restrict__ Qw, const float* __restrict__ Kw,
                            const float* __restrict__ Vw, const float* __restrict__ Pw,
                            const float* __restrict__ rpb, const int* __restrict__ rpi,
                            unsigned short* __restrict__ wbf, float* __restrict__ bias) {
  int idx = blockIdx.x * 256 + threadIdx.x;
  if (idx < 4 * 65536) {
    int which = idx >> 16, e = idx & 65535;
    const float* s = (which == 0) ? Qw : (which == 1) ? Kw : (which == 2) ? Vw : Pw;
    wbf[idx] = f2bf(s[e]);
  }
  if (idx < 8 * NTOK * NTOK) {
    int h = idx / (NTOK * NTOK), ij = idx % (NTOK * NTOK);
    bias[idx] = rpb[rpi[ij] * 8 + h];
  }
}

// ---------------- kernel 1: gather(roll+partition) + QKV projections ----------------
__global__ __launch_bounds__(256) void qkv_kernel(
    const float* __restrict__ Qin, const float* __restrict__ Kin, const float* __restrict__ Vin,
    const float* __restrict__ Qb,  const float* __restrict__ Kb,  const float* __restrict__ Vb,
    const unsigned short* __restrict__ wbf,
    unsigned short* __restrict__ qws, unsigned short* __restrict__ kws,
    unsigned short* __restrict__ vws) {
  __shared__ unsigned short Xbuf[64 * 256];
  const int blk = blockIdx.x, tid = threadIdx.x;
  const int lane = tid & 63, wid = tid >> 6;
  const int b = blk >> 8, wi = (blk >> 4) & 15, wj = blk & 15;
  const int r0 = lane & 15, kof = (lane >> 4) << 3;

#pragma unroll
  for (int ph = 0; ph < 3; ++ph) {
    const float* src  = (ph == 0) ? Qin : (ph == 1) ? Kin : Vin;
    const float* bias = (ph == 0) ? Qb  : (ph == 1) ? Kb  : Vb;
    unsigned short* dst = (ph == 0) ? qws : (ph == 1) ? kws : vws;
    const float scale = (ph == 0) ? 0.17677669529663687f : 1.0f;  // hd^-0.5 on q

    // gather 49x256 fp32 -> bf16 LDS (rows 49..63 zero)
    for (int idx = tid; idx < 64 * 64; idx += 256) {
      int row = idx >> 6, q4 = idx & 63;
      unsigned v0 = 0, v1 = 0;
      if (row < NTOK) {
        int i = row / 7, j = row - i * 7;
        int h_ = wi * 7 + i + SHIFT; if (h_ >= HH) h_ -= HH;
        int w_ = wj * 7 + j + SHIFT; if (w_ >= WWDIM) w_ -= WWDIM;
        const float4 f = *reinterpret_cast<const float4*>(
            src + ((size_t)((b * HH + h_) * WWDIM + w_) << 8) + (q4 << 2));
        v0 = (unsigned)f2bf(f.x) | ((unsigned)f2bf(f.y) << 16);
        v1 = (unsigned)f2bf(f.z) | ((unsigned)f2bf(f.w) << 16);
      }
      *reinterpret_cast<uint2*>(&Xbuf[swzi(row, q4 << 2, 256)]) = make_uint2(v0, v1);
    }
    __syncthreads();

    // GEMM 64x256 x 256x256^T ; wave owns output cols [wid*64, wid*64+64)
    f32x4_t acc[4][4];
#pragma unroll
    for (int a = 0; a < 4; ++a)
#pragma unroll
      for (int c = 0; c < 4; ++c) acc[a][c] = (f32x4_t){0.f, 0.f, 0.f, 0.f};

    const unsigned short* W = wbf + (ph << 16);
#pragma unroll
    for (int ks = 0; ks < 8; ++ks) {
      const int kk = (ks << 5) + kof;
      bf16x8_t af[4], bw[4];
#pragma unroll
      for (int mi = 0; mi < 4; ++mi) af[mi] = ld8(&Xbuf[swzi((mi << 4) + r0, kk, 256)]);
#pragma unroll
      for (int nj = 0; nj < 4; ++nj)
        bw[nj] = ld8(&W[(((wid << 6) + (nj << 4) + r0) << 8) + kk]);
#pragma unroll
      for (int mi = 0; mi < 4; ++mi)
#pragma unroll
        for (int nj = 0; nj < 4; ++nj)
          acc[mi][nj] = __builtin_amdgcn_mfma_f32_16x16x32_bf16(af[mi], bw[nj], acc[mi][nj], 0, 0, 0);
    }

    // epilogue: + bias, *scale, bf16 store (rows >=49 skipped; packed 49-row stride)
#pragma unroll
    for (int mi = 0; mi < 4; ++mi)
#pragma unroll
      for (int rg = 0; rg < 4; ++rg) {
        const int row = (mi << 4) + ((lane >> 4) << 2) + rg;
        if (row < NTOK) {
          unsigned short* rp = dst + (((size_t)blk * NTOK + row) << 8);
#pragma unroll
          for (int nj = 0; nj < 4; ++nj) {
            const int col = (wid << 6) + (nj << 4) + r0;
            rp[col] = f2bf((acc[mi][nj][rg] + bias[col]) * scale);
          }
        }
      }
    __syncthreads();
  }
}

// ---------------- kernel 2: attention + output projection + scatter ----------------
__global__ __launch_bounds__(256) void attn_kernel(
    const unsigned short* __restrict__ qws, const unsigned short* __restrict__ kws,
    const unsigned short* __restrict__ vws, const unsigned short* __restrict__ wp,
    const float* __restrict__ Pb, const float* __restrict__ bias_t,
    float* __restrict__ out) {
  __shared__ unsigned short Pbuf[4 * 64 * 64];   // per-wave P transpose buffer
  __shared__ unsigned short Abuf[64 * 256];      // attention output (pre-projection)
  const int blk = blockIdx.x, tid = threadIdx.x;
  const int lane = tid & 63, wid = tid >> 6;
  const int b = blk >> 8, wi = (blk >> 4) & 15, wj = blk & 15;
  const int r0 = lane & 15, kof = (lane >> 4) << 3;
  const bool edge = (wi == 15) || (wj == 15);
  const size_t wbase = ((size_t)blk * NTOK) << 8;
  unsigned short* Pme = &Pbuf[wid << 12];

  // per-lane column shift categories (cols depend only on nj)
  int ccat[4];
#pragma unroll
  for (int nj = 0; nj < 4; ++nj) {
    int col = (nj << 4) + r0, cc = 0;
    if (col < NTOK) {
      int ti = col / 7, tj = col - ti * 7;
      int chh = (wi == 15) ? (ti >= 4 ? 2 : 1) : 0;
      int cww = (wj == 15) ? (tj >= 4 ? 2 : 1) : 0;
      cc = chh * 3 + cww;
    }
    ccat[nj] = cc;
  }

#pragma unroll
  for (int hh = 0; hh < 2; ++hh) {
    const int h = (wid << 1) + hh;
    const int co = h << 5;  // head channel offset

    // S = q @ k^T  (K = hd = 32 -> single MFMA per tile)
    f32x4_t s[4][4];
#pragma unroll
    for (int a = 0; a < 4; ++a)
#pragma unroll
      for (int c = 0; c < 4; ++c) s[a][c] = (f32x4_t){0.f, 0.f, 0.f, 0.f};
    bf16x8_t aq[4], bk[4];
#pragma unroll
    for (int mi = 0; mi < 4; ++mi)
      aq[mi] = ld8(&qws[wbase + ((size_t)((mi << 4) + r0) << 8) + co + kof]);
#pragma unroll
    for (int nj = 0; nj < 4; ++nj)
      bk[nj] = ld8(&kws[wbase + ((size_t)((nj << 4) + r0) << 8) + co + kof]);
#pragma unroll
    for (int mi = 0; mi < 4; ++mi)
#pragma unroll
      for (int nj = 0; nj < 4; ++nj)
        s[mi][nj] = __builtin_amdgcn_mfma_f32_16x16x32_bf16(aq[mi], bk[nj], s[mi][nj], 0, 0, 0);

    // bias + shift-mask + row softmax (rows live in 16-lane groups)
    const float* bh = bias_t + h * (NTOK * NTOK);
#pragma unroll
    for (int mi = 0; mi < 4; ++mi)
#pragma unroll
      for (int rg = 0; rg < 4; ++rg) {
        const int row = (mi << 4) + ((lane >> 4) << 2) + rg;
        int rcat = 0;
        if (edge && row < NTOK) {
          int ti = row / 7, tj = row - ti * 7;
          int chh = (wi == 15) ? (ti >= 4 ? 2 : 1) : 0;
          int cww = (wj == 15) ? (tj >= 4 ? 2 : 1) : 0;
          rcat = chh * 3 + cww;
        }
        float vals[4];
        float m = -3e38f;
#pragma unroll
        for (int nj = 0; nj < 4; ++nj) {
          const int col = (nj << 4) + r0;
          float v;
          if (row >= NTOK || col >= NTOK) v = -1e30f;
          else {
            v = s[mi][nj][rg] + bh[row * NTOK + col];
            if (edge && ccat[nj] != rcat) v -= 100.f;
          }
          vals[nj] = v;
          m = fmaxf(m, v);
        }
        m = fmaxf(m, __shfl_xor(m, 1));
        m = fmaxf(m, __shfl_xor(m, 2));
        m = fmaxf(m, __shfl_xor(m, 4));
        m = fmaxf(m, __shfl_xor(m, 8));
        float sum = 0.f;
#pragma unroll
        for (int nj = 0; nj < 4; ++nj) { vals[nj] = __expf(vals[nj] - m); sum += vals[nj]; }
        sum += __shfl_xor(sum, 1);
        sum += __shfl_xor(sum, 2);
        sum += __shfl_xor(sum, 4);
        sum += __shfl_xor(sum, 8);
        const float inv = 1.f / sum;
#pragma unroll
        for (int nj = 0; nj < 4; ++nj)
          Pme[swzi(row, (nj << 4) + r0, 64)] = f2bf(vals[nj] * inv);
      }

    // PV: out(64x32) = P(64x64) @ v(64x32); padded P cols are exactly 0
    f32x4_t o[4][2];
#pragma unroll
    for (int a = 0; a < 4; ++a)
#pragma unroll
      for (int c = 0; c < 2; ++c) o[a][c] = (f32x4_t){0.f, 0.f, 0.f, 0.f};
#pragma unroll
    for (int kk = 0; kk < 2; ++kk) {
      bf16x8_t ap[4], bv[2];
#pragma unroll
      for (int mi = 0; mi < 4; ++mi)
        ap[mi] = ld8(&Pme[swzi((mi << 4) + r0, (kk << 5) + kof, 64)]);
#pragma unroll
      for (int nj = 0; nj < 2; ++nj) {
        union { unsigned short u[8]; bf16x8_t v; } t;
        const int ch = co + (nj << 4) + r0;
#pragma unroll
        for (int j = 0; j < 8; ++j)
          t.u[j] = vws[wbase + ((size_t)((kk << 5) + kof + j) << 8) + ch];
        bv[nj] = t.v;
      }
#pragma unroll
      for (int mi = 0; mi < 4; ++mi)
#pragma unroll
        for (int nj = 0; nj < 2; ++nj)
          o[mi][nj] = __builtin_amdgcn_mfma_f32_16x16x32_bf16(ap[mi], bv[nj], o[mi][nj], 0, 0, 0);
    }
#pragma unroll
    for (int mi = 0; mi < 4; ++mi)
#pragma unroll
      for (int rg = 0; rg < 4; ++rg) {
        const int row = (mi << 4) + ((lane >> 4) << 2) + rg;
#pragma unroll
        for (int nj = 0; nj < 2; ++nj)
          Abuf[swzi(row, co + (nj << 4) + r0, 256)] = f2bf(o[mi][nj][rg]);
      }
  }
  __syncthreads();

  // final projection Y = A @ Pw^T + Pb, scatter with inverse roll
  f32x4_t y[4][4];
#pragma unroll
  for (int a = 0; a < 4; ++a)
#pragma unroll
    for (int c = 0; c < 4; ++c) y[a][c] = (f32x4_t){0.f, 0.f, 0.f, 0.f};
#pragma unroll
  for (int ks = 0; ks < 8; ++ks) {
    const int kk = (ks << 5) + kof;
    bf16x8_t af[4], bw[4];
#pragma unroll
    for (int mi = 0; mi < 4; ++mi) af[mi] = ld8(&Abuf[swzi((mi << 4) + r0, kk, 256)]);
#pragma unroll
    for (int nj = 0; nj < 4; ++nj)
      bw[nj] = ld8(&wp[(((wid << 6) + (nj << 4) + r0) << 8) + kk]);
#pragma unroll
    for (int mi = 0; mi < 4; ++mi)
#pragma unroll
      for (int nj = 0; nj < 4; ++nj)
        y[mi][nj] = __builtin_amdgcn_mfma_f32_16x16x32_bf16(af[mi], bw[nj], y[mi][nj], 0, 0, 0);
  }
#pragma unroll
  for (int mi = 0; mi < 4; ++mi)
#pragma unroll
    for (int rg = 0; rg < 4; ++rg) {
      const int row = (mi << 4) + ((lane >> 4) << 2) + rg;
      if (row < NTOK) {
        const int i = row / 7, j = row - (row / 7) * 7;
        int h_ = wi * 7 + i + SHIFT; if (h_ >= HH) h_ -= HH;
        int w_ = wj * 7 + j + SHIFT; if (w_ >= WWDIM) w_ -= WWDIM;
        float* ob = out + ((size_t)((b * HH + h_) * WWDIM + w_) << 8);
#pragma unroll
        for (int nj = 0; nj < 4; ++nj) {
          const int col = (wid << 6) + (nj << 4) + r0;
          ob[col] = y[mi][nj][rg] + Pb[col];
        }
      }
    }
}

extern "C" void kernel_launch(void* const* d_in, const int* in_sizes, int n_in,
                              void* d_out, int out_size, void* d_ws, size_t ws_size,
                              hipStream_t stream) {
  const float* Q   = (const float*)d_in[0];
  const float* K   = (const float*)d_in[1];
  const float* V   = (const float*)d_in[2];
  const float* Qw  = (const float*)d_in[3];
  const float* Qb  = (const float*)d_in[4];
  const float* Kw  = (const float*)d_in[5];
  const float* Kb  = (const float*)d_in[6];
  const float* Vw  = (const float*)d_in[7];
  const float* Vb  = (const float*)d_in[8];
  const float* Pw  = (const float*)d_in[9];
  const float* Pb  = (const float*)d_in[10];
  const float* rpb = (const float*)d_in[11];
  const int*   rpi = (const int*)d_in[12];

  const size_t S1 = (size_t)NWIN * NTOK * 256;   // elems per q/k/v ws plane
  unsigned short* ws16 = (unsigned short*)d_ws;
  unsigned short* qws = ws16;
  unsigned short* kws = ws16 + S1;
  unsigned short* vws = ws16 + 2 * S1;
  unsigned short* wbf = ws16 + 3 * S1;                       // 4*65536 bf16
  float* bias_t = (float*)(ws16 + 3 * S1 + 4 * 65536);       // 8*49*49 f32

  const size_t need = (3 * S1 + 4 * 65536) * 2 + (size_t)8 * NTOK * NTOK * 4 + 65536;
  if (ws_size < need) return;  // loud failure signal (output stays poisoned)

  prep_kernel<<<1024, 256, 0, stream>>>(Qw, Kw, Vw, Pw, rpb, rpi, wbf, bias_t);
  qkv_kernel<<<NWIN, 256, 0, stream>>>(Q, K, V, Qb, Kb, Vb, wbf, qws, kws, vws);
  attn_kernel<<<NWIN, 256, 0, stream>>>(qws, kws, vws, wbf + 3 * 65536, Pb, bias_t,
                                        (float*)d_out);
}

// Round 2
// 985.509 us; speedup vs baseline: 1.1832x; 1.1832x over previous
//
#include <hip/hip_runtime.h>

// ShiftedWindowAttention on MI355X (gfx950), bf16 MFMA implementation.
// B=16, H=W=112, C=256, NH=8, hd=32, window 7x7 (N=49), shift 3, nWin=4096.
// Workspace layout (bf16 elems unless noted):
//   qws [4096*49][256] | kws [4096*49][256] | vT [4096][256][64] |
//   wbf [4][256][256] | bias f32 [8][49][49]    (~340 MB)

typedef short  bf16x8_t __attribute__((ext_vector_type(8)));
typedef float  f32x4_t  __attribute__((ext_vector_type(4)));
typedef int    i32x4_t  __attribute__((ext_vector_type(4)));

#define HH    112
#define WWDIM 112
#define NTOK  49
#define NWIN  4096
#define SHIFT 3

__device__ __forceinline__ unsigned short f2bf(float f) {
  unsigned u = __builtin_bit_cast(unsigned, f);
  u += 0x7FFFu + ((u >> 16) & 1u);           // RNE
  return (unsigned short)(u >> 16);
}

__device__ __forceinline__ bf16x8_t ld8(const unsigned short* p) {
  return __builtin_bit_cast(bf16x8_t, *reinterpret_cast<const i32x4_t*>(p));
}

// XOR-swizzled index (ushort units) shared by writer+reader. rowElems = bf16/row.
__device__ __forceinline__ int swzi(int row, int col, int rowElems) {
  int by = col << 1;
  int sb = (((by >> 4) ^ (row & 7)) << 4) | (by & 15);
  return row * rowElems + (sb >> 1);
}

// ---------------- prep: weights -> bf16, bias table ----------------
__global__ void prep_kernel(const float* __restrict__ Qw, const float* __restrict__ Kw,
                            const float* __restrict__ Vw, const float* __restrict__ Pw,
                            const float* __restrict__ rpb, const int* __restrict__ rpi,
                            unsigned short* __restrict__ wbf, float* __restrict__ bias) {
  int idx = blockIdx.x * 256 + threadIdx.x;
  if (idx < 4 * 65536) {
    int which = idx >> 16, e = idx & 65535;
    const float* s = (which == 0) ? Qw : (which == 1) ? Kw : (which == 2) ? Vw : Pw;
    wbf[idx] = f2bf(s[e]);
  }
  if (idx < 8 * NTOK * NTOK) {
    int h = idx / (NTOK * NTOK), ij = idx % (NTOK * NTOK);
    bias[idx] = rpb[rpi[ij] * 8 + h];
  }
}

// ---------------- kernel 1: gather(roll+partition) + QKV projections ----------------
// Per phase: hoist the wave's full weight slice (64 cols x 256 K) into 128 VGPRs,
// so the k-loop is pure LDS + MFMA with no global loads on the critical path.
__global__ __launch_bounds__(256, 2) void qkv_kernel(
    const float* __restrict__ Qin, const float* __restrict__ Kin, const float* __restrict__ Vin,
    const float* __restrict__ Qb,  const float* __restrict__ Kb,  const float* __restrict__ Vb,
    const unsigned short* __restrict__ wbf,
    unsigned short* __restrict__ qws, unsigned short* __restrict__ kws,
    unsigned short* __restrict__ vT) {
  __shared__ unsigned short Xbuf[64 * 256];
  const int blk = blockIdx.x, tid = threadIdx.x;
  const int lane = tid & 63, wid = tid >> 6;
  const int b = blk >> 8, wi = (blk >> 4) & 15, wj = blk & 15;
  const int r0 = lane & 15, kof = (lane >> 4) << 3;

#pragma unroll
  for (int ph = 0; ph < 3; ++ph) {
    const float* src  = (ph == 0) ? Qin : (ph == 1) ? Kin : Vin;
    const float* bias = (ph == 0) ? Qb  : (ph == 1) ? Kb  : Vb;
    const float scale = (ph == 0) ? 0.17677669529663687f : 1.0f;  // hd^-0.5 on q

    // gather 49x256 fp32 -> bf16 LDS (rows 49..63 zero)
#pragma unroll
    for (int it = 0; it < 16; ++it) {
      int idx = tid + it * 256;
      int row = idx >> 6, q4 = idx & 63;
      unsigned v0 = 0, v1 = 0;
      if (row < NTOK) {
        int i = row / 7, j = row - i * 7;
        int h_ = wi * 7 + i + SHIFT; if (h_ >= HH) h_ -= HH;
        int w_ = wj * 7 + j + SHIFT; if (w_ >= WWDIM) w_ -= WWDIM;
        const float4 f = *reinterpret_cast<const float4*>(
            src + ((size_t)((b * HH + h_) * WWDIM + w_) << 8) + (q4 << 2));
        v0 = (unsigned)f2bf(f.x) | ((unsigned)f2bf(f.y) << 16);
        v1 = (unsigned)f2bf(f.z) | ((unsigned)f2bf(f.w) << 16);
      }
      *reinterpret_cast<uint2*>(&Xbuf[swzi(row, q4 << 2, 256)]) = make_uint2(v0, v1);
    }

    // hoist full weight slice for this wave (issued before the barrier; overlaps gather)
    const unsigned short* W = wbf + (ph << 16);
    bf16x8_t bw[8][4];
#pragma unroll
    for (int ks = 0; ks < 8; ++ks)
#pragma unroll
      for (int nj = 0; nj < 4; ++nj)
        bw[ks][nj] = ld8(&W[(((wid << 6) + (nj << 4) + r0) << 8) + (ks << 5) + kof]);

    __syncthreads();

    f32x4_t acc[4][4];
#pragma unroll
    for (int a = 0; a < 4; ++a)
#pragma unroll
      for (int c = 0; c < 4; ++c) acc[a][c] = (f32x4_t){0.f, 0.f, 0.f, 0.f};

#pragma unroll
    for (int ks = 0; ks < 8; ++ks) {
      const int kk = (ks << 5) + kof;
      bf16x8_t af[4];
#pragma unroll
      for (int mi = 0; mi < 4; ++mi) af[mi] = ld8(&Xbuf[swzi((mi << 4) + r0, kk, 256)]);
#pragma unroll
      for (int mi = 0; mi < 4; ++mi)
#pragma unroll
        for (int nj = 0; nj < 4; ++nj)
          acc[mi][nj] = __builtin_amdgcn_mfma_f32_16x16x32_bf16(af[mi], bw[ks][nj], acc[mi][nj], 0, 0, 0);
    }

    // epilogue: + bias, *scale, bf16 store
#pragma unroll
    for (int mi = 0; mi < 4; ++mi)
#pragma unroll
      for (int rg = 0; rg < 4; ++rg) {
        const int row = (mi << 4) + ((lane >> 4) << 2) + rg;
        if (row < NTOK) {
          if (ph < 2) {
            unsigned short* rp = ((ph == 0) ? qws : kws) + (((size_t)blk * NTOK + row) << 8);
#pragma unroll
            for (int nj = 0; nj < 4; ++nj) {
              const int col = (wid << 6) + (nj << 4) + r0;
              rp[col] = f2bf((acc[mi][nj][rg] + bias[col]) * scale);
            }
          } else {
            // V: store transposed [win][ch 256][tok 64] for vector PV loads
            unsigned short* vp = vT + ((size_t)blk << 14);
#pragma unroll
            for (int nj = 0; nj < 4; ++nj) {
              const int col = (wid << 6) + (nj << 4) + r0;
              vp[(col << 6) + row] = f2bf(acc[mi][nj][rg] + bias[col]);
            }
          }
        }
      }
    __syncthreads();
  }
}

// ---------------- kernel 2: attention + output projection + scatter ----------------
__global__ __launch_bounds__(256) void attn_kernel(
    const unsigned short* __restrict__ qws, const unsigned short* __restrict__ kws,
    const unsigned short* __restrict__ vT, const unsigned short* __restrict__ wp,
    const float* __restrict__ Pb, const float* __restrict__ bias_t,
    float* __restrict__ out) {
  __shared__ unsigned short Pbuf[4 * 64 * 64];   // per-wave P transpose buffer
  __shared__ unsigned short Abuf[64 * 256];      // attention output (pre-projection)
  const int blk = blockIdx.x, tid = threadIdx.x;
  const int lane = tid & 63, wid = tid >> 6;
  const int b = blk >> 8, wi = (blk >> 4) & 15, wj = blk & 15;
  const int r0 = lane & 15, kof = (lane >> 4) << 3;
  const bool edge = (wi == 15) || (wj == 15);
  const size_t wbase = ((size_t)blk * NTOK) << 8;
  const unsigned short* vTb = vT + ((size_t)blk << 14);
  unsigned short* Pme = &Pbuf[wid << 12];

  // per-lane column shift categories (cols depend only on nj)
  int ccat[4];
#pragma unroll
  for (int nj = 0; nj < 4; ++nj) {
    int col = (nj << 4) + r0, cc = 0;
    if (col < NTOK) {
      int ti = col / 7, tj = col - ti * 7;
      int chh = (wi == 15) ? (ti >= 4 ? 2 : 1) : 0;
      int cww = (wj == 15) ? (tj >= 4 ? 2 : 1) : 0;
      cc = chh * 3 + cww;
    }
    ccat[nj] = cc;
  }

#pragma unroll
  for (int hh = 0; hh < 2; ++hh) {
    const int h = (wid << 1) + hh;
    const int co = h << 5;  // head channel offset

    // S = q @ k^T  (K = hd = 32 -> single MFMA per tile)
    f32x4_t s[4][4];
#pragma unroll
    for (int a = 0; a < 4; ++a)
#pragma unroll
      for (int c = 0; c < 4; ++c) s[a][c] = (f32x4_t){0.f, 0.f, 0.f, 0.f};
    bf16x8_t aq[4], bk[4];
#pragma unroll
    for (int mi = 0; mi < 4; ++mi)
      aq[mi] = ld8(&qws[wbase + ((size_t)((mi << 4) + r0) << 8) + co + kof]);
#pragma unroll
    for (int nj = 0; nj < 4; ++nj)
      bk[nj] = ld8(&kws[wbase + ((size_t)((nj << 4) + r0) << 8) + co + kof]);
#pragma unroll
    for (int mi = 0; mi < 4; ++mi)
#pragma unroll
      for (int nj = 0; nj < 4; ++nj)
        s[mi][nj] = __builtin_amdgcn_mfma_f32_16x16x32_bf16(aq[mi], bk[nj], s[mi][nj], 0, 0, 0);

    // bias + shift-mask + row softmax (rows live in 16-lane groups)
    const float* bh = bias_t + h * (NTOK * NTOK);
#pragma unroll
    for (int mi = 0; mi < 4; ++mi)
#pragma unroll
      for (int rg = 0; rg < 4; ++rg) {
        const int row = (mi << 4) + ((lane >> 4) << 2) + rg;
        int rcat = 0;
        if (edge && row < NTOK) {
          int ti = row / 7, tj = row - ti * 7;
          int chh = (wi == 15) ? (ti >= 4 ? 2 : 1) : 0;
          int cww = (wj == 15) ? (tj >= 4 ? 2 : 1) : 0;
          rcat = chh * 3 + cww;
        }
        float vals[4];
        float m = -3e38f;
#pragma unroll
        for (int nj = 0; nj < 4; ++nj) {
          const int col = (nj << 4) + r0;
          float v;
          if (row >= NTOK || col >= NTOK) v = -1e30f;
          else {
            v = s[mi][nj][rg] + bh[row * NTOK + col];
            if (edge && ccat[nj] != rcat) v -= 100.f;
          }
          vals[nj] = v;
          m = fmaxf(m, v);
        }
        m = fmaxf(m, __shfl_xor(m, 1));
        m = fmaxf(m, __shfl_xor(m, 2));
        m = fmaxf(m, __shfl_xor(m, 4));
        m = fmaxf(m, __shfl_xor(m, 8));
        float sum = 0.f;
#pragma unroll
        for (int nj = 0; nj < 4; ++nj) { vals[nj] = __expf(vals[nj] - m); sum += vals[nj]; }
        sum += __shfl_xor(sum, 1);
        sum += __shfl_xor(sum, 2);
        sum += __shfl_xor(sum, 4);
        sum += __shfl_xor(sum, 8);
        const float inv = 1.f / sum;
#pragma unroll
        for (int nj = 0; nj < 4; ++nj)
          Pme[swzi(row, (nj << 4) + r0, 64)] = f2bf(vals[nj] * inv);
      }

    // PV: out(64x32) = P(64x64) @ v(64x32); padded P cols are exactly 0
    f32x4_t o[4][2];
#pragma unroll
    for (int a = 0; a < 4; ++a)
#pragma unroll
      for (int c = 0; c < 2; ++c) o[a][c] = (f32x4_t){0.f, 0.f, 0.f, 0.f};
#pragma unroll
    for (int kk = 0; kk < 2; ++kk) {
      bf16x8_t ap[4], bv[2];
#pragma unroll
      for (int mi = 0; mi < 4; ++mi)
        ap[mi] = ld8(&Pme[swzi((mi << 4) + r0, (kk << 5) + kof, 64)]);
#pragma unroll
      for (int nj = 0; nj < 2; ++nj)
        bv[nj] = ld8(&vTb[((co + (nj << 4) + r0) << 6) + (kk << 5) + kof]);
#pragma unroll
      for (int mi = 0; mi < 4; ++mi)
#pragma unroll
        for (int nj = 0; nj < 2; ++nj)
          o[mi][nj] = __builtin_amdgcn_mfma_f32_16x16x32_bf16(ap[mi], bv[nj], o[mi][nj], 0, 0, 0);
    }
#pragma unroll
    for (int mi = 0; mi < 4; ++mi)
#pragma unroll
      for (int rg = 0; rg < 4; ++rg) {
        const int row = (mi << 4) + ((lane >> 4) << 2) + rg;
#pragma unroll
        for (int nj = 0; nj < 2; ++nj)
          Abuf[swzi(row, co + (nj << 4) + r0, 256)] = f2bf(o[mi][nj][rg]);
      }
  }
  __syncthreads();

  // final projection Y = A @ Pw^T + Pb, scatter with inverse roll
  f32x4_t y[4][4];
#pragma unroll
  for (int a = 0; a < 4; ++a)
#pragma unroll
    for (int c = 0; c < 4; ++c) y[a][c] = (f32x4_t){0.f, 0.f, 0.f, 0.f};
#pragma unroll
  for (int ks = 0; ks < 8; ++ks) {
    const int kk = (ks << 5) + kof;
    bf16x8_t af[4], bw[4];
#pragma unroll
    for (int mi = 0; mi < 4; ++mi) af[mi] = ld8(&Abuf[swzi((mi << 4) + r0, kk, 256)]);
#pragma unroll
    for (int nj = 0; nj < 4; ++nj)
      bw[nj] = ld8(&wp[(((wid << 6) + (nj << 4) + r0) << 8) + kk]);
#pragma unroll
    for (int mi = 0; mi < 4; ++mi)
#pragma unroll
      for (int nj = 0; nj < 4; ++nj)
        y[mi][nj] = __builtin_amdgcn_mfma_f32_16x16x32_bf16(af[mi], bw[nj], y[mi][nj], 0, 0, 0);
  }
#pragma unroll
  for (int mi = 0; mi < 4; ++mi)
#pragma unroll
    for (int rg = 0; rg < 4; ++rg) {
      const int row = (mi << 4) + ((lane >> 4) << 2) + rg;
      if (row < NTOK) {
        const int i = row / 7, j = row - (row / 7) * 7;
        int h_ = wi * 7 + i + SHIFT; if (h_ >= HH) h_ -= HH;
        int w_ = wj * 7 + j + SHIFT; if (w_ >= WWDIM) w_ -= WWDIM;
        float* ob = out + ((size_t)((b * HH + h_) * WWDIM + w_) << 8);
#pragma unroll
        for (int nj = 0; nj < 4; ++nj) {
          const int col = (wid << 6) + (nj << 4) + r0;
          ob[col] = y[mi][nj][rg] + Pb[col];
        }
      }
    }
}

extern "C" void kernel_launch(void* const* d_in, const int* in_sizes, int n_in,
                              void* d_out, int out_size, void* d_ws, size_t ws_size,
                              hipStream_t stream) {
  const float* Q   = (const float*)d_in[0];
  const float* K   = (const float*)d_in[1];
  const float* V   = (const float*)d_in[2];
  const float* Qw  = (const float*)d_in[3];
  const float* Qb  = (const float*)d_in[4];
  const float* Kw  = (const float*)d_in[5];
  const float* Kb  = (const float*)d_in[6];
  const float* Vw  = (const float*)d_in[7];
  const float* Vb  = (const float*)d_in[8];
  const float* Pw  = (const float*)d_in[9];
  const float* Pb  = (const float*)d_in[10];
  const float* rpb = (const float*)d_in[11];
  const int*   rpi = (const int*)d_in[12];

  const size_t S1  = (size_t)NWIN * NTOK * 256;   // elems per q/k ws plane
  const size_t VTE = (size_t)NWIN * 256 * 64;     // vT elems
  unsigned short* ws16 = (unsigned short*)d_ws;
  unsigned short* qws = ws16;
  unsigned short* kws = ws16 + S1;
  unsigned short* vT  = ws16 + 2 * S1;
  unsigned short* wbf = ws16 + 2 * S1 + VTE;                  // 4*65536 bf16
  float* bias_t = (float*)(ws16 + 2 * S1 + VTE + 4 * 65536);  // 8*49*49 f32

  const size_t need = (2 * S1 + VTE + 4 * 65536) * 2 + (size_t)8 * NTOK * NTOK * 4 + 65536;
  if (ws_size < need) return;  // loud failure signal (output stays poisoned)

  prep_kernel<<<1024, 256, 0, stream>>>(Qw, Kw, Vw, Pw, rpb, rpi, wbf, bias_t);
  qkv_kernel<<<NWIN, 256, 0, stream>>>(Q, K, V, Qb, Kb, Vb, wbf, qws, kws, vT);
  attn_kernel<<<NWIN, 256, 0, stream>>>(qws, kws, vT, wbf + 3 * 65536, Pb, bias_t,
                                        (float*)d_out);
}

// Round 3
// 775.490 us; speedup vs baseline: 1.5037x; 1.2708x over previous
//
#include <hip/hip_runtime.h>

// ShiftedWindowAttention on MI355X (gfx950) — fully fused bf16 MFMA kernel.
// B=16, H=W=112, C=256, NH=8, hd=32, window 7x7 (N=49), shift 3, nWin=4096.
// One block per window: gather(roll) -> QKV GEMMs -> attention -> out proj -> scatter.
// LDS = 128 KB: X(32K, reused as P) | q(32K, reused as attn-out) | k(32K) | vT(32K).
// Workspace: wbf (4x256x256 bf16 weights) + bias f32 [8][49][49]  (~600 KB).

typedef short  bf16x8_t __attribute__((ext_vector_type(8)));
typedef float  f32x4_t  __attribute__((ext_vector_type(4)));
typedef int    i32x4_t  __attribute__((ext_vector_type(4)));

#define HH    112
#define WWDIM 112
#define NTOK  49
#define NWIN  4096
#define SHIFT 3

__device__ __forceinline__ unsigned short f2bf(float f) {
  unsigned u = __builtin_bit_cast(unsigned, f);
  u += 0x7FFFu + ((u >> 16) & 1u);           // RNE
  return (unsigned short)(u >> 16);
}

__device__ __forceinline__ bf16x8_t ld8(const unsigned short* p) {
  return __builtin_bit_cast(bf16x8_t, *reinterpret_cast<const i32x4_t*>(p));
}

// XOR-swizzled index (ushort units) shared by writer+reader. rowElems = bf16/row.
__device__ __forceinline__ int swzi(int row, int col, int rowElems) {
  int by = col << 1;
  int sb = (((by >> 4) ^ (row & 7)) << 4) | (by & 15);
  return row * rowElems + (sb >> 1);
}

// ---------------- prep: weights -> bf16, bias table ----------------
__global__ void prep_kernel(const float* __restrict__ Qw, const float* __restrict__ Kw,
                            const float* __restrict__ Vw, const float* __restrict__ Pw,
                            const float* __restrict__ rpb, const int* __restrict__ rpi,
                            unsigned short* __restrict__ wbf, float* __restrict__ bias) {
  int idx = blockIdx.x * 256 + threadIdx.x;
  if (idx < 4 * 65536) {
    int which = idx >> 16, e = idx & 65535;
    const float* s = (which == 0) ? Qw : (which == 1) ? Kw : (which == 2) ? Vw : Pw;
    wbf[idx] = f2bf(s[e]);
  }
  if (idx < 8 * NTOK * NTOK) {
    int h = idx / (NTOK * NTOK), ij = idx % (NTOK * NTOK);
    bias[idx] = rpb[rpi[ij] * 8 + h];
  }
}

// staged global gather of one 49x256 fp32 window slice into float4 regs
#define GLOAD(SRC)                                                            \
  do {                                                                        \
    _Pragma("unroll") for (int it = 0; it < 16; ++it) {                       \
      if (((tid >> 6) + (it << 2)) < NTOK)                                    \
        g[it] = *reinterpret_cast<const float4*>((SRC) + goff[it]);           \
      else                                                                    \
        g[it] = make_float4(0.f, 0.f, 0.f, 0.f);                              \
    }                                                                         \
  } while (0)

// write staged regs -> Xs (bf16, swizzled)
#define XWRITE()                                                              \
  do {                                                                        \
    _Pragma("unroll") for (int it = 0; it < 16; ++it) {                       \
      unsigned v0 = (unsigned)f2bf(g[it].x) | ((unsigned)f2bf(g[it].y) << 16);\
      unsigned v1 = (unsigned)f2bf(g[it].z) | ((unsigned)f2bf(g[it].w) << 16);\
      *reinterpret_cast<uint2*>(                                              \
          &Xs[swzi((tid >> 6) + (it << 2), (tid & 63) << 2, 256)]) =          \
          make_uint2(v0, v1);                                                 \
    }                                                                         \
  } while (0)

// hoist one weight matrix's wave-slice (64 cols x 256 K) into bw[8][4]
#define WHOIST(PH)                                                            \
  do {                                                                        \
    const unsigned short* W_ = wbf + ((PH) << 16);                            \
    _Pragma("unroll") for (int ks = 0; ks < 8; ++ks)                          \
        _Pragma("unroll") for (int nj = 0; nj < 4; ++nj)                      \
            bw[ks][nj] =                                                      \
        ld8(&W_[(((wid << 6) + (nj << 4) + r0) << 8) + (ks << 5) + kof]);     \
  } while (0)

__global__ __launch_bounds__(256, 1) void fused_kernel(
    const float* __restrict__ Qin, const float* __restrict__ Kin, const float* __restrict__ Vin,
    const float* __restrict__ Qbv, const float* __restrict__ Kbv, const float* __restrict__ Vbv,
    const float* __restrict__ Pbv,
    const unsigned short* __restrict__ wbf, const float* __restrict__ bias_t,
    float* __restrict__ out) {
  __shared__ unsigned short Xs[64 * 256];   // staging; later per-wave P buffers
  __shared__ unsigned short Qs[64 * 256];   // q; later attention output
  __shared__ unsigned short Ks[64 * 256];   // k
  __shared__ unsigned short Vs[256 * 64];   // v transposed [ch][tok]

  const int blk = blockIdx.x, tid = threadIdx.x;
  const int lane = tid & 63, wid = tid >> 6;
  const int b = blk >> 8, wi = (blk >> 4) & 15, wj = blk & 15;
  const int r0 = lane & 15, kof = (lane >> 4) << 3;

  // gather geometry: element offsets (same for Q/K/V)
  unsigned goff[16];
#pragma unroll
  for (int it = 0; it < 16; ++it) {
    int row = (tid >> 6) + (it << 2), q4 = tid & 63;
    unsigned off = 0;
    if (row < NTOK) {
      int i = row / 7, j = row - i * 7;
      int h_ = wi * 7 + i + SHIFT; if (h_ >= HH) h_ -= HH;
      int w_ = wj * 7 + j + SHIFT; if (w_ >= WWDIM) w_ -= WWDIM;
      off = ((unsigned)((b * HH + h_) * WWDIM + w_) << 8) + (q4 << 2);
    }
    goff[it] = off;
  }

  float4 g[16];
  bf16x8_t bw[8][4];

  GLOAD(Qin);
  XWRITE();
  WHOIST(0);
  __syncthreads();

#pragma unroll
  for (int ph = 0; ph < 3; ++ph) {
    // prefetch next phase's gather while this GEMM runs (T14)
    if (ph == 0) GLOAD(Kin);
    else if (ph == 1) GLOAD(Vin);

    f32x4_t acc[4][4];
#pragma unroll
    for (int a = 0; a < 4; ++a)
#pragma unroll
      for (int c = 0; c < 4; ++c) acc[a][c] = (f32x4_t){0.f, 0.f, 0.f, 0.f};

#pragma unroll
    for (int ks = 0; ks < 8; ++ks) {
      const int kk = (ks << 5) + kof;
      bf16x8_t af[4];
#pragma unroll
      for (int mi = 0; mi < 4; ++mi) af[mi] = ld8(&Xs[swzi((mi << 4) + r0, kk, 256)]);
#pragma unroll
      for (int mi = 0; mi < 4; ++mi)
#pragma unroll
        for (int nj = 0; nj < 4; ++nj)
          acc[mi][nj] = __builtin_amdgcn_mfma_f32_16x16x32_bf16(af[mi], bw[ks][nj], acc[mi][nj], 0, 0, 0);
    }

    const float* bias = (ph == 0) ? Qbv : (ph == 1) ? Kbv : Vbv;
    float bb[4];
#pragma unroll
    for (int nj = 0; nj < 4; ++nj) bb[nj] = bias[(wid << 6) + (nj << 4) + r0];

#pragma unroll
    for (int mi = 0; mi < 4; ++mi)
#pragma unroll
      for (int rg = 0; rg < 4; ++rg) {
        const int row = (mi << 4) + ((lane >> 4) << 2) + rg;
#pragma unroll
        for (int nj = 0; nj < 4; ++nj) {
          const int col = (wid << 6) + (nj << 4) + r0;
          const float val = acc[mi][nj][rg] + bb[nj];
          if (ph == 0)      Qs[swzi(row, col, 256)] = f2bf(val * 0.17677669529663687f);
          else if (ph == 1) Ks[swzi(row, col, 256)] = f2bf(val);
          else              Vs[swzi(col, row, 64)]  = f2bf(val);
        }
      }
    __syncthreads();
    if (ph < 2) {
      XWRITE();
      WHOIST(ph + 1);
      __syncthreads();
    }
  }

  // ---------------- attention (wave wid owns heads 2*wid, 2*wid+1) ----------------
  const bool edge = (wi == 15) || (wj == 15);
  unsigned short* Pme = &Xs[wid << 12];

  int ccat[4];
#pragma unroll
  for (int nj = 0; nj < 4; ++nj) {
    int col = (nj << 4) + r0, cc = 0;
    if (col < NTOK) {
      int ti = col / 7, tj = col - ti * 7;
      int chh = (wi == 15) ? (ti >= 4 ? 2 : 1) : 0;
      int cww = (wj == 15) ? (tj >= 4 ? 2 : 1) : 0;
      cc = chh * 3 + cww;
    }
    ccat[nj] = cc;
  }

#pragma unroll
  for (int hh = 0; hh < 2; ++hh) {
    const int h = (wid << 1) + hh;
    const int co = h << 5;  // head channel offset

    // S = q @ k^T from LDS fragments
    f32x4_t s[4][4];
#pragma unroll
    for (int a = 0; a < 4; ++a)
#pragma unroll
      for (int c = 0; c < 4; ++c) s[a][c] = (f32x4_t){0.f, 0.f, 0.f, 0.f};
    bf16x8_t aq[4], bk[4];
#pragma unroll
    for (int mi = 0; mi < 4; ++mi)
      aq[mi] = ld8(&Qs[swzi((mi << 4) + r0, co + kof, 256)]);
#pragma unroll
    for (int nj = 0; nj < 4; ++nj)
      bk[nj] = ld8(&Ks[swzi((nj << 4) + r0, co + kof, 256)]);
#pragma unroll
    for (int mi = 0; mi < 4; ++mi)
#pragma unroll
      for (int nj = 0; nj < 4; ++nj)
        s[mi][nj] = __builtin_amdgcn_mfma_f32_16x16x32_bf16(aq[mi], bk[nj], s[mi][nj], 0, 0, 0);

    // bias + shift-mask + row softmax
    const float* bh = bias_t + h * (NTOK * NTOK);
#pragma unroll
    for (int mi = 0; mi < 4; ++mi)
#pragma unroll
      for (int rg = 0; rg < 4; ++rg) {
        const int row = (mi << 4) + ((lane >> 4) << 2) + rg;
        int rcat = 0;
        if (edge && row < NTOK) {
          int ti = row / 7, tj = row - ti * 7;
          int chh = (wi == 15) ? (ti >= 4 ? 2 : 1) : 0;
          int cww = (wj == 15) ? (tj >= 4 ? 2 : 1) : 0;
          rcat = chh * 3 + cww;
        }
        float vals[4];
        float m = -3e38f;
#pragma unroll
        for (int nj = 0; nj < 4; ++nj) {
          const int col = (nj << 4) + r0;
          float v;
          if (row >= NTOK || col >= NTOK) v = -1e30f;
          else {
            v = s[mi][nj][rg] + bh[row * NTOK + col];
            if (edge && ccat[nj] != rcat) v -= 100.f;
          }
          vals[nj] = v;
          m = fmaxf(m, v);
        }
        m = fmaxf(m, __shfl_xor(m, 1));
        m = fmaxf(m, __shfl_xor(m, 2));
        m = fmaxf(m, __shfl_xor(m, 4));
        m = fmaxf(m, __shfl_xor(m, 8));
        float sum = 0.f;
#pragma unroll
        for (int nj = 0; nj < 4; ++nj) { vals[nj] = __expf(vals[nj] - m); sum += vals[nj]; }
        sum += __shfl_xor(sum, 1);
        sum += __shfl_xor(sum, 2);
        sum += __shfl_xor(sum, 4);
        sum += __shfl_xor(sum, 8);
        const float inv = 1.f / sum;
#pragma unroll
        for (int nj = 0; nj < 4; ++nj)
          Pme[swzi(row, (nj << 4) + r0, 64)] = f2bf(vals[nj] * inv);
      }

    // PV: out(64x32) = P(64x64) @ v(64x32)
    f32x4_t o[4][2];
#pragma unroll
    for (int a = 0; a < 4; ++a)
#pragma unroll
      for (int c = 0; c < 2; ++c) o[a][c] = (f32x4_t){0.f, 0.f, 0.f, 0.f};
#pragma unroll
    for (int kk = 0; kk < 2; ++kk) {
      bf16x8_t ap[4], bv[2];
#pragma unroll
      for (int mi = 0; mi < 4; ++mi)
        ap[mi] = ld8(&Pme[swzi((mi << 4) + r0, (kk << 5) + kof, 64)]);
#pragma unroll
      for (int nj = 0; nj < 2; ++nj)
        bv[nj] = ld8(&Vs[swzi(co + (nj << 4) + r0, (kk << 5) + kof, 64)]);
#pragma unroll
      for (int mi = 0; mi < 4; ++mi)
#pragma unroll
        for (int nj = 0; nj < 2; ++nj)
          o[mi][nj] = __builtin_amdgcn_mfma_f32_16x16x32_bf16(ap[mi], bv[nj], o[mi][nj], 0, 0, 0);
    }
    // attn-out overwrites this wave's own q columns (no cross-wave hazard)
#pragma unroll
    for (int mi = 0; mi < 4; ++mi)
#pragma unroll
      for (int rg = 0; rg < 4; ++rg) {
        const int row = (mi << 4) + ((lane >> 4) << 2) + rg;
#pragma unroll
        for (int nj = 0; nj < 2; ++nj)
          Qs[swzi(row, co + (nj << 4) + r0, 256)] = f2bf(o[mi][nj][rg]);
      }
  }
  __syncthreads();

  // ---------------- final projection Y = A @ Pw^T + Pb, scatter with inverse roll ----------------
  WHOIST(3);
  float pb[4];
#pragma unroll
  for (int nj = 0; nj < 4; ++nj) pb[nj] = Pbv[(wid << 6) + (nj << 4) + r0];

  f32x4_t y[4][4];
#pragma unroll
  for (int a = 0; a < 4; ++a)
#pragma unroll
    for (int c = 0; c < 4; ++c) y[a][c] = (f32x4_t){0.f, 0.f, 0.f, 0.f};
#pragma unroll
  for (int ks = 0; ks < 8; ++ks) {
    const int kk = (ks << 5) + kof;
    bf16x8_t af[4];
#pragma unroll
    for (int mi = 0; mi < 4; ++mi) af[mi] = ld8(&Qs[swzi((mi << 4) + r0, kk, 256)]);
#pragma unroll
    for (int mi = 0; mi < 4; ++mi)
#pragma unroll
      for (int nj = 0; nj < 4; ++nj)
        y[mi][nj] = __builtin_amdgcn_mfma_f32_16x16x32_bf16(af[mi], bw[ks][nj], y[mi][nj], 0, 0, 0);
  }
#pragma unroll
  for (int mi = 0; mi < 4; ++mi)
#pragma unroll
    for (int rg = 0; rg < 4; ++rg) {
      const int row = (mi << 4) + ((lane >> 4) << 2) + rg;
      if (row < NTOK) {
        const int i = row / 7, j = row - (row / 7) * 7;
        int h_ = wi * 7 + i + SHIFT; if (h_ >= HH) h_ -= HH;
        int w_ = wj * 7 + j + SHIFT; if (w_ >= WWDIM) w_ -= WWDIM;
        float* ob = out + ((size_t)((b * HH + h_) * WWDIM + w_) << 8);
#pragma unroll
        for (int nj = 0; nj < 4; ++nj) {
          const int col = (wid << 6) + (nj << 4) + r0;
          ob[col] = y[mi][nj][rg] + pb[nj];
        }
      }
    }
}

extern "C" void kernel_launch(void* const* d_in, const int* in_sizes, int n_in,
                              void* d_out, int out_size, void* d_ws, size_t ws_size,
                              hipStream_t stream) {
  const float* Q   = (const float*)d_in[0];
  const float* K   = (const float*)d_in[1];
  const float* V   = (const float*)d_in[2];
  const float* Qw  = (const float*)d_in[3];
  const float* Qb  = (const float*)d_in[4];
  const float* Kw  = (const float*)d_in[5];
  const float* Kb  = (const float*)d_in[6];
  const float* Vw  = (const float*)d_in[7];
  const float* Vb  = (const float*)d_in[8];
  const float* Pw  = (const float*)d_in[9];
  const float* Pb  = (const float*)d_in[10];
  const float* rpb = (const float*)d_in[11];
  const int*   rpi = (const int*)d_in[12];

  unsigned short* wbf = (unsigned short*)d_ws;                 // 4*65536 bf16
  float* bias_t = (float*)(wbf + 4 * 65536);                   // 8*49*49 f32

  const size_t need = (size_t)4 * 65536 * 2 + (size_t)8 * NTOK * NTOK * 4;
  if (ws_size < need) return;  // loud failure signal (output stays poisoned)

  prep_kernel<<<1024, 256, 0, stream>>>(Qw, Kw, Vw, Pw, rpb, rpi, wbf, bias_t);
  fused_kernel<<<NWIN, 256, 0, stream>>>(Q, K, V, Qb, Kb, Vb, Pb, wbf, bias_t,
                                         (float*)d_out);
}

// Round 4
// 569.652 us; speedup vs baseline: 2.0470x; 1.3613x over previous
//
#include <hip/hip_runtime.h>

// ShiftedWindowAttention on MI355X (gfx950) — fully fused bf16 MFMA kernel.
// B=16, H=W=112, C=256, NH=8, hd=32, window 7x7 (N=49), shift 3, nWin=4096.
// One 512-thread block per window (8 waves, 1 head/wave in attention).
// Swapped-operand GEMMs (D^T = W·X^T) so epilogue C-fragments walk channels
// per lane -> packed 8B LDS stores / float4 global stores.
// LDS = 128 KB: Xs(32K, ->P w0..3) | Qs(32K, ->attn-out) | Ks(32K, ->P w4..7) | Vs(32K).

typedef short  bf16x8_t __attribute__((ext_vector_type(8)));
typedef float  f32x4_t  __attribute__((ext_vector_type(4)));
typedef int    i32x4_t  __attribute__((ext_vector_type(4)));

#define HH    112
#define WWDIM 112
#define NTOK  49
#define NWIN  4096
#define SHIFT 3

__device__ __forceinline__ unsigned short f2bf(float f) {
  unsigned u = __builtin_bit_cast(unsigned, f);
  u += 0x7FFFu + ((u >> 16) & 1u);           // RNE
  return (unsigned short)(u >> 16);
}

__device__ __forceinline__ bf16x8_t ld8(const unsigned short* p) {
  return __builtin_bit_cast(bf16x8_t, *reinterpret_cast<const i32x4_t*>(p));
}

// XOR-swizzled index (ushort units) shared by writer+reader. rowElems = bf16/row.
__device__ __forceinline__ int swzi(int row, int col, int rowElems) {
  int by = col << 1;
  int sb = (((by >> 4) ^ (row & 7)) << 4) | (by & 15);
  return row * rowElems + (sb >> 1);
}

// ---------------- prep: weights -> bf16, bias table ----------------
__global__ void prep_kernel(const float* __restrict__ Qw, const float* __restrict__ Kw,
                            const float* __restrict__ Vw, const float* __restrict__ Pw,
                            const float* __restrict__ rpb, const int* __restrict__ rpi,
                            unsigned short* __restrict__ wbf, float* __restrict__ bias) {
  int idx = blockIdx.x * 256 + threadIdx.x;
  if (idx < 4 * 65536) {
    int which = idx >> 16, e = idx & 65535;
    const float* s = (which == 0) ? Qw : (which == 1) ? Kw : (which == 2) ? Vw : Pw;
    wbf[idx] = f2bf(s[e]);
  }
  if (idx < 8 * NTOK * NTOK) {
    int h = idx / (NTOK * NTOK), ij = idx % (NTOK * NTOK);
    bias[idx] = rpb[rpi[ij] * 8 + h];
  }
}

#define GLOAD(SRC)                                                            \
  do {                                                                        \
    _Pragma("unroll") for (int it = 0; it < 8; ++it) {                        \
      g[it] = ((wid + (it << 3)) < NTOK)                                      \
                  ? *reinterpret_cast<const float4*>((SRC) + goff[it])        \
                  : make_float4(0.f, 0.f, 0.f, 0.f);                          \
    }                                                                         \
  } while (0)

#define XWRITE()                                                              \
  do {                                                                        \
    _Pragma("unroll") for (int it = 0; it < 8; ++it) {                        \
      unsigned v0 = (unsigned)f2bf(g[it].x) | ((unsigned)f2bf(g[it].y) << 16);\
      unsigned v1 = (unsigned)f2bf(g[it].z) | ((unsigned)f2bf(g[it].w) << 16);\
      *reinterpret_cast<uint2*>(                                              \
          &Xs[swzi(wid + (it << 3), lane << 2, 256)]) = make_uint2(v0, v1);   \
    }                                                                         \
  } while (0)

// hoist one weight matrix's wave-slice (32 rows x 256 K) into bw[8][2]
#define WHOIST(PH)                                                            \
  do {                                                                        \
    const unsigned short* W_ = wbf + ((PH) << 16);                            \
    _Pragma("unroll") for (int ks = 0; ks < 8; ++ks)                          \
        _Pragma("unroll") for (int t = 0; t < 2; ++t)                         \
            bw[ks][t] =                                                       \
        ld8(&W_[(((wid << 5) + (t << 4) + r0) << 8) + (ks << 5) + kof]);      \
  } while (0)

__global__ __launch_bounds__(512, 2) void fused_kernel(
    const float* __restrict__ Qin, const float* __restrict__ Kin, const float* __restrict__ Vin,
    const float* __restrict__ Qbv, const float* __restrict__ Kbv, const float* __restrict__ Vbv,
    const float* __restrict__ Pbv,
    const unsigned short* __restrict__ wbf, const float* __restrict__ bias_t,
    float* __restrict__ out) {
  __shared__ unsigned short Xs[64 * 256];   // staging; later P for waves 0..3
  __shared__ unsigned short Qs[64 * 256];   // q [tok][ch]; later attn-out
  __shared__ unsigned short Ks[64 * 256];   // k [tok][ch]; later P for waves 4..7
  __shared__ unsigned short Vs[256 * 64];   // v transposed [ch][tok]

  const int blk = blockIdx.x, tid = threadIdx.x;
  const int lane = tid & 63, wid = tid >> 6;            // 8 waves
  const int b = blk >> 8, wi = (blk >> 4) & 15, wj = blk & 15;
  const int r0 = lane & 15, g4 = (lane >> 4) << 2, kof = (lane >> 4) << 3;

  // gather geometry: element offsets (same for Q/K/V); wave handles rows wid+8*it
  unsigned goff[8];
#pragma unroll
  for (int it = 0; it < 8; ++it) {
    int row = wid + (it << 3);
    unsigned off = 0;
    if (row < NTOK) {
      int i = row / 7, j = row - i * 7;
      int h_ = wi * 7 + i + SHIFT; if (h_ >= HH) h_ -= HH;
      int w_ = wj * 7 + j + SHIFT; if (w_ >= WWDIM) w_ -= WWDIM;
      off = ((unsigned)((b * HH + h_) * WWDIM + w_) << 8) + (lane << 2);
    }
    goff[it] = off;
  }

  float4 g[8];
  bf16x8_t bw[8][2];

  GLOAD(Qin);
  XWRITE();
  WHOIST(0);
  __syncthreads();

  // ---------------- QKV projections ----------------
#pragma unroll
  for (int ph = 0; ph < 3; ++ph) {
    if (ph == 0) GLOAD(Kin);
    else if (ph == 1) GLOAD(Vin);

    if (ph < 2) {
      // swapped: D[ch][tok] = sum_k W[ch][k] X[tok][k]; wave owns ch [wid*32..+32)
      f32x4_t acc[2][4];
#pragma unroll
      for (int a = 0; a < 2; ++a)
#pragma unroll
        for (int c = 0; c < 4; ++c) acc[a][c] = (f32x4_t){0.f, 0.f, 0.f, 0.f};
#pragma unroll
      for (int ks = 0; ks < 8; ++ks) {
        const int kk = (ks << 5) + kof;
        bf16x8_t xb[4];
#pragma unroll
        for (int nj = 0; nj < 4; ++nj) xb[nj] = ld8(&Xs[swzi((nj << 4) + r0, kk, 256)]);
#pragma unroll
        for (int mi = 0; mi < 2; ++mi)
#pragma unroll
          for (int nj = 0; nj < 4; ++nj)
            acc[mi][nj] = __builtin_amdgcn_mfma_f32_16x16x32_bf16(bw[ks][mi], xb[nj], acc[mi][nj], 0, 0, 0);
      }
      const float* bias = ph ? Kbv : Qbv;
      const float scale = ph ? 1.0f : 0.17677669529663687f;
      unsigned short* dst = ph ? Ks : Qs;
#pragma unroll
      for (int mi = 0; mi < 2; ++mi) {
        const int ch0 = (wid << 5) + (mi << 4) + g4;
        const float4 bb = *reinterpret_cast<const float4*>(bias + ch0);
#pragma unroll
        for (int nj = 0; nj < 4; ++nj) {
          const int tok = (nj << 4) + r0;
          unsigned u0 = (unsigned)f2bf((acc[mi][nj][0] + bb.x) * scale) |
                        ((unsigned)f2bf((acc[mi][nj][1] + bb.y) * scale) << 16);
          unsigned u1 = (unsigned)f2bf((acc[mi][nj][2] + bb.z) * scale) |
                        ((unsigned)f2bf((acc[mi][nj][3] + bb.w) * scale) << 16);
          *reinterpret_cast<uint2*>(&dst[swzi(tok, ch0, 256)]) = make_uint2(u0, u1);
        }
      }
    } else {
      // unswapped: D[tok][ch]; lane walks tokens -> packed store into Vs[ch][tok]
      f32x4_t acc[4][2];
#pragma unroll
      for (int a = 0; a < 4; ++a)
#pragma unroll
        for (int c = 0; c < 2; ++c) acc[a][c] = (f32x4_t){0.f, 0.f, 0.f, 0.f};
#pragma unroll
      for (int ks = 0; ks < 8; ++ks) {
        const int kk = (ks << 5) + kof;
        bf16x8_t xa[4];
#pragma unroll
        for (int mi = 0; mi < 4; ++mi) xa[mi] = ld8(&Xs[swzi((mi << 4) + r0, kk, 256)]);
#pragma unroll
        for (int mi = 0; mi < 4; ++mi)
#pragma unroll
          for (int t = 0; t < 2; ++t)
            acc[mi][t] = __builtin_amdgcn_mfma_f32_16x16x32_bf16(xa[mi], bw[ks][t], acc[mi][t], 0, 0, 0);
      }
      float bbv[2];
#pragma unroll
      for (int t = 0; t < 2; ++t) bbv[t] = Vbv[(wid << 5) + (t << 4) + r0];
#pragma unroll
      for (int mi = 0; mi < 4; ++mi)
#pragma unroll
        for (int t = 0; t < 2; ++t) {
          const int ch = (wid << 5) + (t << 4) + r0;
          const int tok0 = (mi << 4) + g4;
          unsigned u0 = (unsigned)f2bf(acc[mi][t][0] + bbv[t]) |
                        ((unsigned)f2bf(acc[mi][t][1] + bbv[t]) << 16);
          unsigned u1 = (unsigned)f2bf(acc[mi][t][2] + bbv[t]) |
                        ((unsigned)f2bf(acc[mi][t][3] + bbv[t]) << 16);
          *reinterpret_cast<uint2*>(&Vs[swzi(ch, tok0, 64)]) = make_uint2(u0, u1);
        }
    }
    __syncthreads();
    if (ph < 2) {
      XWRITE();
      WHOIST(ph + 1);
      __syncthreads();
    }
  }

  // ---------------- attention: wave wid owns head wid ----------------
  const bool edge = (wi == 15) || (wj == 15);
  const int co = wid << 5;
  unsigned short* Pme = (wid < 4) ? &Xs[wid << 12] : &Ks[(wid - 4) << 12];

  int ccat[4];
#pragma unroll
  for (int nj = 0; nj < 4; ++nj) {
    int col = (nj << 4) + r0, cc = 0;
    if (col < NTOK) {
      int ti = col / 7, tj = col - ti * 7;
      int chh = (wi == 15) ? (ti >= 4 ? 2 : 1) : 0;
      int cww = (wj == 15) ? (tj >= 4 ? 2 : 1) : 0;
      cc = chh * 3 + cww;
    }
    ccat[nj] = cc;
  }

  // S = q @ k^T  (K = hd = 32 -> single MFMA per tile)
  f32x4_t s[4][4];
  bf16x8_t aq[4], bk[4];
#pragma unroll
  for (int mi = 0; mi < 4; ++mi) aq[mi] = ld8(&Qs[swzi((mi << 4) + r0, co + kof, 256)]);
#pragma unroll
  for (int nj = 0; nj < 4; ++nj) bk[nj] = ld8(&Ks[swzi((nj << 4) + r0, co + kof, 256)]);
  __builtin_amdgcn_s_setprio(1);
#pragma unroll
  for (int mi = 0; mi < 4; ++mi)
#pragma unroll
    for (int nj = 0; nj < 4; ++nj)
      s[mi][nj] = __builtin_amdgcn_mfma_f32_16x16x32_bf16(aq[mi], bk[nj], (f32x4_t){0.f, 0.f, 0.f, 0.f}, 0, 0, 0);
  __builtin_amdgcn_s_setprio(0);

  // bias + shift-mask + softmax, normalized in place into s
  const float* bh = bias_t + wid * (NTOK * NTOK);
#pragma unroll
  for (int mi = 0; mi < 4; ++mi)
#pragma unroll
    for (int rg = 0; rg < 4; ++rg) {
      const int row = (mi << 4) + g4 + rg;
      int rcat = 0;
      if (edge && row < NTOK) {
        int ti = row / 7, tj = row - ti * 7;
        int chh = (wi == 15) ? (ti >= 4 ? 2 : 1) : 0;
        int cww = (wj == 15) ? (tj >= 4 ? 2 : 1) : 0;
        rcat = chh * 3 + cww;
      }
      float vals[4];
      float m = -3e38f;
#pragma unroll
      for (int nj = 0; nj < 4; ++nj) {
        const int col = (nj << 4) + r0;
        float v;
        if (row >= NTOK || col >= NTOK) v = -1e30f;
        else {
          v = s[mi][nj][rg] + bh[row * NTOK + col];
          if (edge && ccat[nj] != rcat) v -= 100.f;
        }
        vals[nj] = v;
        m = fmaxf(m, v);
      }
      m = fmaxf(m, __shfl_xor(m, 1));
      m = fmaxf(m, __shfl_xor(m, 2));
      m = fmaxf(m, __shfl_xor(m, 4));
      m = fmaxf(m, __shfl_xor(m, 8));
      float sum = 0.f;
#pragma unroll
      for (int nj = 0; nj < 4; ++nj) { vals[nj] = __expf(vals[nj] - m); sum += vals[nj]; }
      sum += __shfl_xor(sum, 1);
      sum += __shfl_xor(sum, 2);
      sum += __shfl_xor(sum, 4);
      sum += __shfl_xor(sum, 8);
      const float inv = 1.f / sum;
#pragma unroll
      for (int nj = 0; nj < 4; ++nj) s[mi][nj][rg] = vals[nj] * inv;
    }

  __syncthreads();   // all waves done reading Qs/Ks -> safe to overwrite with P / attn-out
  WHOIST(3);         // Pw hoist overlaps P-store + PV

  // P -> LDS (per-wave region)
#pragma unroll
  for (int mi = 0; mi < 4; ++mi)
#pragma unroll
    for (int rg = 0; rg < 4; ++rg) {
      const int row = (mi << 4) + g4 + rg;
#pragma unroll
      for (int nj = 0; nj < 4; ++nj)
        Pme[swzi(row, (nj << 4) + r0, 64)] = f2bf(s[mi][nj][rg]);
    }

  // PV swapped: O^T[ch][qtok] = sum_kt V[kt][ch] P[qtok][kt]
  f32x4_t o[2][4];
#pragma unroll
  for (int a = 0; a < 2; ++a)
#pragma unroll
    for (int c = 0; c < 4; ++c) o[a][c] = (f32x4_t){0.f, 0.f, 0.f, 0.f};
#pragma unroll
  for (int kk = 0; kk < 2; ++kk) {
    bf16x8_t va[2], pbf[4];
#pragma unroll
    for (int t = 0; t < 2; ++t)
      va[t] = ld8(&Vs[swzi(co + (t << 4) + r0, (kk << 5) + kof, 64)]);
#pragma unroll
    for (int nj = 0; nj < 4; ++nj)
      pbf[nj] = ld8(&Pme[swzi((nj << 4) + r0, (kk << 5) + kof, 64)]);
    __builtin_amdgcn_s_setprio(1);
#pragma unroll
    for (int t = 0; t < 2; ++t)
#pragma unroll
      for (int nj = 0; nj < 4; ++nj)
        o[t][nj] = __builtin_amdgcn_mfma_f32_16x16x32_bf16(va[t], pbf[nj], o[t][nj], 0, 0, 0);
    __builtin_amdgcn_s_setprio(0);
  }

  // attn-out -> Qs[tok][ch] (packed 8B writes; wave-exclusive channel slice)
#pragma unroll
  for (int t = 0; t < 2; ++t)
#pragma unroll
    for (int nj = 0; nj < 4; ++nj) {
      const int tok = (nj << 4) + r0;
      const int ch0 = co + (t << 4) + g4;
      unsigned u0 = (unsigned)f2bf(o[t][nj][0]) | ((unsigned)f2bf(o[t][nj][1]) << 16);
      unsigned u1 = (unsigned)f2bf(o[t][nj][2]) | ((unsigned)f2bf(o[t][nj][3]) << 16);
      *reinterpret_cast<uint2*>(&Qs[swzi(tok, ch0, 256)]) = make_uint2(u0, u1);
    }
  __syncthreads();

  // ---------------- final projection (swapped) + scatter with inverse roll ----------------
  f32x4_t y[2][4];
#pragma unroll
  for (int a = 0; a < 2; ++a)
#pragma unroll
    for (int c = 0; c < 4; ++c) y[a][c] = (f32x4_t){0.f, 0.f, 0.f, 0.f};
#pragma unroll
  for (int ks = 0; ks < 8; ++ks) {
    const int kk = (ks << 5) + kof;
    bf16x8_t xb[4];
#pragma unroll
    for (int nj = 0; nj < 4; ++nj) xb[nj] = ld8(&Qs[swzi((nj << 4) + r0, kk, 256)]);
#pragma unroll
    for (int mi = 0; mi < 2; ++mi)
#pragma unroll
      for (int nj = 0; nj < 4; ++nj)
        y[mi][nj] = __builtin_amdgcn_mfma_f32_16x16x32_bf16(bw[ks][mi], xb[nj], y[mi][nj], 0, 0, 0);
  }
  float4 pb[2];
#pragma unroll
  for (int mi = 0; mi < 2; ++mi)
    pb[mi] = *reinterpret_cast<const float4*>(Pbv + (wid << 5) + (mi << 4) + g4);
#pragma unroll
  for (int nj = 0; nj < 4; ++nj) {
    const int tok = (nj << 4) + r0;
    if (tok < NTOK) {
      const int i = tok / 7, j = tok - (tok / 7) * 7;
      int h_ = wi * 7 + i + SHIFT; if (h_ >= HH) h_ -= HH;
      int w_ = wj * 7 + j + SHIFT; if (w_ >= WWDIM) w_ -= WWDIM;
      float* ob = out + ((size_t)((b * HH + h_) * WWDIM + w_) << 8);
#pragma unroll
      for (int mi = 0; mi < 2; ++mi) {
        const int ch0 = (wid << 5) + (mi << 4) + g4;
        *reinterpret_cast<float4*>(ob + ch0) =
            make_float4(y[mi][nj][0] + pb[mi].x, y[mi][nj][1] + pb[mi].y,
                        y[mi][nj][2] + pb[mi].z, y[mi][nj][3] + pb[mi].w);
      }
    }
  }
}

extern "C" void kernel_launch(void* const* d_in, const int* in_sizes, int n_in,
                              void* d_out, int out_size, void* d_ws, size_t ws_size,
                              hipStream_t stream) {
  const float* Q   = (const float*)d_in[0];
  const float* K   = (const float*)d_in[1];
  const float* V   = (const float*)d_in[2];
  const float* Qw  = (const float*)d_in[3];
  const float* Qb  = (const float*)d_in[4];
  const float* Kw  = (const float*)d_in[5];
  const float* Kb  = (const float*)d_in[6];
  const float* Vw  = (const float*)d_in[7];
  const float* Vb  = (const float*)d_in[8];
  const float* Pw  = (const float*)d_in[9];
  const float* Pb  = (const float*)d_in[10];
  const float* rpb = (const float*)d_in[11];
  const int*   rpi = (const int*)d_in[12];

  unsigned short* wbf = (unsigned short*)d_ws;                 // 4*65536 bf16
  float* bias_t = (float*)(wbf + 4 * 65536);                   // 8*49*49 f32

  const size_t need = (size_t)4 * 65536 * 2 + (size_t)8 * NTOK * NTOK * 4;
  if (ws_size < need) return;  // loud failure signal (output stays poisoned)

  prep_kernel<<<1024, 256, 0, stream>>>(Qw, Kw, Vw, Pw, rpb, rpi, wbf, bias_t);
  fused_kernel<<<NWIN, 512, 0, stream>>>(Q, K, V, Qb, Kb, Vb, Pb, wbf, bias_t,
                                         (float*)d_out);
}

// Round 5
// 459.650 us; speedup vs baseline: 2.5369x; 1.2393x over previous
//
#include <hip/hip_runtime.h>

// ShiftedWindowAttention on MI355X (gfx950) — fused, register-resident attention.
// B=16, H=W=112, C=256, NH=8, hd=32, window 7x7 (N=49), shift 3, nWin=4096.
// 512-thread block per window; wave wid owns head wid (channels [32wid,32wid+32)).
// Swapped QKV GEMMs leave q/k (and V via unswapped GEMM) in exactly the
// mfma_16x16x16 fragment layouts -> QK^T/softmax/PV run entirely in registers.
// LDS = 32 KB: X staging (per phase), then attention output for the final proj.

typedef short  bf16x4_t __attribute__((ext_vector_type(4)));
typedef short  bf16x8_t __attribute__((ext_vector_type(8)));
typedef float  f32x4_t  __attribute__((ext_vector_type(4)));
typedef int    i32x4_t  __attribute__((ext_vector_type(4)));

#define HH    112
#define WWDIM 112
#define NTOK  49
#define NWIN  4096
#define SHIFT 3

__device__ __forceinline__ unsigned short f2bf(float f) {
  unsigned u = __builtin_bit_cast(unsigned, f);
  u += 0x7FFFu + ((u >> 16) & 1u);           // RNE
  return (unsigned short)(u >> 16);
}

__device__ __forceinline__ bf16x8_t ld8(const unsigned short* p) {
  return __builtin_bit_cast(bf16x8_t, *reinterpret_cast<const i32x4_t*>(p));
}

__device__ __forceinline__ bf16x4_t pack4(float a, float b, float c, float d) {
  union { unsigned short u[4]; bf16x4_t v; } t;
  t.u[0] = f2bf(a); t.u[1] = f2bf(b); t.u[2] = f2bf(c); t.u[3] = f2bf(d);
  return t.v;
}

// XOR-swizzled index (ushort units) shared by writer+reader. rowElems = bf16/row.
__device__ __forceinline__ int swzi(int row, int col, int rowElems) {
  int by = col << 1;
  int sb = (((by >> 4) ^ (row & 7)) << 4) | (by & 15);
  return row * rowElems + (sb >> 1);
}

// ---------------- prep: weights -> bf16, bias table transposed to [h][kt][qt] ----------------
__global__ void prep_kernel(const float* __restrict__ Qw, const float* __restrict__ Kw,
                            const float* __restrict__ Vw, const float* __restrict__ Pw,
                            const float* __restrict__ rpb, const int* __restrict__ rpi,
                            unsigned short* __restrict__ wbf, float* __restrict__ biasT) {
  int idx = blockIdx.x * 256 + threadIdx.x;
  if (idx < 4 * 65536) {
    int which = idx >> 16, e = idx & 65535;
    const float* s = (which == 0) ? Qw : (which == 1) ? Kw : (which == 2) ? Vw : Pw;
    wbf[idx] = f2bf(s[e]);
  }
  if (idx < 8 * NTOK * NTOK) {
    int h = idx / (NTOK * NTOK), ij = idx % (NTOK * NTOK);
    int i = ij / NTOK, j = ij - (ij / NTOK) * NTOK;   // i = query tok, j = key tok
    biasT[h * (NTOK * NTOK) + j * NTOK + i] = rpb[rpi[ij] * 8 + h];
  }
}

#define GLOAD(SRC)                                                            \
  do {                                                                        \
    _Pragma("unroll") for (int it = 0; it < 8; ++it) {                        \
      g[it] = ((wid + (it << 3)) < NTOK)                                      \
                  ? *reinterpret_cast<const float4*>((SRC) + goff[it])        \
                  : make_float4(0.f, 0.f, 0.f, 0.f);                          \
    }                                                                         \
  } while (0)

#define XWRITE()                                                              \
  do {                                                                        \
    _Pragma("unroll") for (int it = 0; it < 8; ++it) {                        \
      unsigned v0 = (unsigned)f2bf(g[it].x) | ((unsigned)f2bf(g[it].y) << 16);\
      unsigned v1 = (unsigned)f2bf(g[it].z) | ((unsigned)f2bf(g[it].w) << 16);\
      *reinterpret_cast<uint2*>(                                              \
          &Xs[swzi(wid + (it << 3), lane << 2, 256)]) = make_uint2(v0, v1);   \
    }                                                                         \
  } while (0)

// hoist one weight matrix's wave-slice (32 rows x 256 K) into bw[8][2]
#define WHOIST(PH)                                                            \
  do {                                                                        \
    const unsigned short* W_ = wbf + ((PH) << 16);                            \
    _Pragma("unroll") for (int ks = 0; ks < 8; ++ks)                          \
        _Pragma("unroll") for (int t = 0; t < 2; ++t)                         \
            bw[ks][t] =                                                       \
        ld8(&W_[(((wid << 5) + (t << 4) + lo) << 8) + (ks << 5) + kof]);      \
  } while (0)

__global__ __launch_bounds__(512, 2) void fused_kernel(
    const float* __restrict__ Qin, const float* __restrict__ Kin, const float* __restrict__ Vin,
    const float* __restrict__ Qbv, const float* __restrict__ Kbv, const float* __restrict__ Vbv,
    const float* __restrict__ Pbv,
    const unsigned short* __restrict__ wbf, const float* __restrict__ biasT,
    float* __restrict__ out) {
  __shared__ unsigned short Xs[64 * 256];   // X staging per phase; then attn-out

  const int blk = blockIdx.x, tid = threadIdx.x;
  const int lane = tid & 63, wid = tid >> 6;            // 8 waves, head wid
  const int b = blk >> 8, wi = (blk >> 4) & 15, wj = blk & 15;
  const int lo = lane & 15, hi = lane >> 4;
  const int g4 = hi << 2, kof = hi << 3;

  // gather geometry (roll by SHIFT); wave handles rows wid+8*it
  unsigned goff[8];
#pragma unroll
  for (int it = 0; it < 8; ++it) {
    int row = wid + (it << 3);
    unsigned off = 0;
    if (row < NTOK) {
      int i = row / 7, j = row - i * 7;
      int h_ = wi * 7 + i + SHIFT; if (h_ >= HH) h_ -= HH;
      int w_ = wj * 7 + j + SHIFT; if (w_ >= WWDIM) w_ -= WWDIM;
      off = ((unsigned)((b * HH + h_) * WWDIM + w_) << 8) + (lane << 2);
    }
    goff[it] = off;
  }

  float4 g[8];
  bf16x8_t bw[8][2];
  bf16x4_t qf[2][4], kf[2][4], vf[4][2];

  GLOAD(Qin);
  WHOIST(0);
  XWRITE();
  __syncthreads();

  // ---------------- Q and K projections (swapped: D[ch][tok]) ----------------
#pragma unroll
  for (int ph = 0; ph < 2; ++ph) {
    GLOAD(ph == 0 ? Kin : Vin);   // prefetch next staging while GEMM runs
    f32x4_t acc[2][4];
#pragma unroll
    for (int a = 0; a < 2; ++a)
#pragma unroll
      for (int c = 0; c < 4; ++c) acc[a][c] = (f32x4_t){0.f, 0.f, 0.f, 0.f};
#pragma unroll
    for (int ks = 0; ks < 8; ++ks) {
      const int kk = (ks << 5) + kof;
      bf16x8_t xb[4];
#pragma unroll
      for (int nj = 0; nj < 4; ++nj) xb[nj] = ld8(&Xs[swzi((nj << 4) + lo, kk, 256)]);
#pragma unroll
      for (int mi = 0; mi < 2; ++mi)
#pragma unroll
        for (int nj = 0; nj < 4; ++nj)
          acc[mi][nj] = __builtin_amdgcn_mfma_f32_16x16x32_bf16(bw[ks][mi], xb[nj], acc[mi][nj], 0, 0, 0);
    }
    const float* bias = (ph == 0) ? Qbv : Kbv;
    const float scale = (ph == 0) ? 0.17677669529663687f : 1.0f;
    bf16x4_t (*dst)[4] = (ph == 0) ? qf : kf;
#pragma unroll
    for (int mi = 0; mi < 2; ++mi) {
      const float4 bb = *reinterpret_cast<const float4*>(bias + (wid << 5) + (mi << 4) + g4);
#pragma unroll
      for (int nj = 0; nj < 4; ++nj)
        dst[mi][nj] = pack4((acc[mi][nj][0] + bb.x) * scale, (acc[mi][nj][1] + bb.y) * scale,
                            (acc[mi][nj][2] + bb.z) * scale, (acc[mi][nj][3] + bb.w) * scale);
    }
    __syncthreads();
    WHOIST(ph + 1);
    XWRITE();
    __syncthreads();
  }

  // ---------------- V projection (unswapped: D[tok][ch]) ----------------
  {
    f32x4_t acc[4][2];
#pragma unroll
    for (int a = 0; a < 4; ++a)
#pragma unroll
      for (int c = 0; c < 2; ++c) acc[a][c] = (f32x4_t){0.f, 0.f, 0.f, 0.f};
#pragma unroll
    for (int ks = 0; ks < 8; ++ks) {
      const int kk = (ks << 5) + kof;
      bf16x8_t xa[4];
#pragma unroll
      for (int mi = 0; mi < 4; ++mi) xa[mi] = ld8(&Xs[swzi((mi << 4) + lo, kk, 256)]);
#pragma unroll
      for (int mi = 0; mi < 4; ++mi)
#pragma unroll
        for (int t = 0; t < 2; ++t)
          acc[mi][t] = __builtin_amdgcn_mfma_f32_16x16x32_bf16(xa[mi], bw[ks][t], acc[mi][t], 0, 0, 0);
    }
    float bbv[2];
#pragma unroll
    for (int t = 0; t < 2; ++t) bbv[t] = Vbv[(wid << 5) + (t << 4) + lo];
#pragma unroll
    for (int mi = 0; mi < 4; ++mi)
#pragma unroll
      for (int t = 0; t < 2; ++t)
        vf[mi][t] = pack4(acc[mi][t][0] + bbv[t], acc[mi][t][1] + bbv[t],
                          acc[mi][t][2] + bbv[t], acc[mi][t][3] + bbv[t]);
  }
  WHOIST(3);   // Pw hoist overlaps attention

  // ---------------- attention, fully in registers ----------------
  const bool wi15 = (wi == 15), wj15 = (wj == 15);
  // key-token bits per (njk, rg): kt = 16*njk + 4*hi + rg
  unsigned kbi = 0, kbj = 0, kval = 0;
#pragma unroll
  for (int njk = 0; njk < 4; ++njk)
#pragma unroll
    for (int rg = 0; rg < 4; ++rg) {
      int kt = (njk << 4) + g4 + rg;
      if (kt < NTOK) {
        int ti = kt / 7, tj = kt - (kt / 7) * 7;
        unsigned bit = 1u << (njk * 4 + rg);
        kval |= bit;
        if (ti >= 4) kbi |= bit;
        if (tj >= 4) kbj |= bit;
      }
    }

  // S^T[kt][qt] = sum_ch k·q  (K=16 MFMAs straight from QKV accumulator frags)
  f32x4_t st[4][4];
  __builtin_amdgcn_s_setprio(1);
#pragma unroll
  for (int njk = 0; njk < 4; ++njk)
#pragma unroll
    for (int njq = 0; njq < 4; ++njq) {
      st[njk][njq] = __builtin_amdgcn_mfma_f32_16x16x16bf16_1k(
          kf[0][njk], qf[0][njq], (f32x4_t){0.f, 0.f, 0.f, 0.f}, 0, 0, 0);
      st[njk][njq] = __builtin_amdgcn_mfma_f32_16x16x16bf16_1k(
          kf[1][njk], qf[1][njq], st[njk][njq], 0, 0, 0);
    }
  __builtin_amdgcn_s_setprio(0);

  // bias + shift mask + softmax (row qt = 16*njq + lo; reduce over hi via 2 shfls)
  const float* bh = biasT + wid * (NTOK * NTOK);
  bf16x4_t pf[4][4];
#pragma unroll
  for (int njq = 0; njq < 4; ++njq) {
    const int qt = (njq << 4) + lo;
    const bool qv = qt < NTOK;
    const int sqt = qv ? qt : 0;
    const int qti = sqt / 7, qtj = sqt - (sqt / 7) * 7;
    const bool qbi = qti >= 4, qbj = qtj >= 4;
    float vals[4][4];
    float m = -3e38f;
#pragma unroll
    for (int njk = 0; njk < 4; ++njk)
#pragma unroll
      for (int rg = 0; rg < 4; ++rg) {
        const int bit = njk * 4 + rg;
        const int kt = (njk << 4) + g4 + rg;
        const bool valid = qv && ((kval >> bit) & 1u);
        float v = st[njk][njq][rg] + bh[(valid ? kt : 0) * NTOK + sqt];
        if (wi15 && (qbi != (bool)((kbi >> bit) & 1u))) v -= 100.f;
        if (wj15 && (qbj != (bool)((kbj >> bit) & 1u))) v -= 100.f;
        v = valid ? v : -1e30f;
        vals[njk][rg] = v;
        m = fmaxf(m, v);
      }
    m = fmaxf(m, __shfl_xor(m, 16));
    m = fmaxf(m, __shfl_xor(m, 32));
    float sum = 0.f;
#pragma unroll
    for (int njk = 0; njk < 4; ++njk)
#pragma unroll
      for (int rg = 0; rg < 4; ++rg) {
        const float e = __expf(vals[njk][rg] - m);
        vals[njk][rg] = e;
        sum += e;
      }
    sum += __shfl_xor(sum, 16);
    sum += __shfl_xor(sum, 32);
    const float inv = 1.f / sum;
#pragma unroll
    for (int njk = 0; njk < 4; ++njk)
      pf[njk][njq] = pack4(vals[njk][0] * inv, vals[njk][1] * inv,
                           vals[njk][2] * inv, vals[njk][3] * inv);
  }

  // PV: O^T[ch][qt] = sum_kt V^T[ch][kt] P^T[kt][qt] — frags straight from regs
  f32x4_t o[2][4];
#pragma unroll
  for (int a = 0; a < 2; ++a)
#pragma unroll
    for (int c = 0; c < 4; ++c) o[a][c] = (f32x4_t){0.f, 0.f, 0.f, 0.f};
  __builtin_amdgcn_s_setprio(1);
#pragma unroll
  for (int mi = 0; mi < 4; ++mi)
#pragma unroll
    for (int t = 0; t < 2; ++t)
#pragma unroll
      for (int njq = 0; njq < 4; ++njq)
        o[t][njq] = __builtin_amdgcn_mfma_f32_16x16x16bf16_1k(vf[mi][t], pf[mi][njq], o[t][njq], 0, 0, 0);
  __builtin_amdgcn_s_setprio(0);

  __syncthreads();   // all waves past their V-GEMM Xs reads -> reuse Xs as attn-out
#pragma unroll
  for (int t = 0; t < 2; ++t)
#pragma unroll
    for (int njq = 0; njq < 4; ++njq) {
      const int qt = (njq << 4) + lo;
      const int ch0 = (wid << 5) + (t << 4) + g4;
      unsigned u0 = (unsigned)f2bf(o[t][njq][0]) | ((unsigned)f2bf(o[t][njq][1]) << 16);
      unsigned u1 = (unsigned)f2bf(o[t][njq][2]) | ((unsigned)f2bf(o[t][njq][3]) << 16);
      *reinterpret_cast<uint2*>(&Xs[swzi(qt, ch0, 256)]) = make_uint2(u0, u1);
    }
  __syncthreads();

  // ---------------- final projection (swapped) + scatter with inverse roll ----------------
  f32x4_t y[2][4];
#pragma unroll
  for (int a = 0; a < 2; ++a)
#pragma unroll
    for (int c = 0; c < 4; ++c) y[a][c] = (f32x4_t){0.f, 0.f, 0.f, 0.f};
#pragma unroll
  for (int ks = 0; ks < 8; ++ks) {
    const int kk = (ks << 5) + kof;
    bf16x8_t xb[4];
#pragma unroll
    for (int nj = 0; nj < 4; ++nj) xb[nj] = ld8(&Xs[swzi((nj << 4) + lo, kk, 256)]);
#pragma unroll
    for (int mi = 0; mi < 2; ++mi)
#pragma unroll
      for (int nj = 0; nj < 4; ++nj)
        y[mi][nj] = __builtin_amdgcn_mfma_f32_16x16x32_bf16(bw[ks][mi], xb[nj], y[mi][nj], 0, 0, 0);
  }
  float4 pb[2];
#pragma unroll
  for (int mi = 0; mi < 2; ++mi)
    pb[mi] = *reinterpret_cast<const float4*>(Pbv + (wid << 5) + (mi << 4) + g4);
#pragma unroll
  for (int nj = 0; nj < 4; ++nj) {
    const int tok = (nj << 4) + lo;
    if (tok < NTOK) {
      const int i = tok / 7, j = tok - (tok / 7) * 7;
      int h_ = wi * 7 + i + SHIFT; if (h_ >= HH) h_ -= HH;
      int w_ = wj * 7 + j + SHIFT; if (w_ >= WWDIM) w_ -= WWDIM;
      float* ob = out + ((size_t)((b * HH + h_) * WWDIM + w_) << 8);
#pragma unroll
      for (int mi = 0; mi < 2; ++mi) {
        const int ch0 = (wid << 5) + (mi << 4) + g4;
        *reinterpret_cast<float4*>(ob + ch0) =
            make_float4(y[mi][nj][0] + pb[mi].x, y[mi][nj][1] + pb[mi].y,
                        y[mi][nj][2] + pb[mi].z, y[mi][nj][3] + pb[mi].w);
      }
    }
  }
}

extern "C" void kernel_launch(void* const* d_in, const int* in_sizes, int n_in,
                              void* d_out, int out_size, void* d_ws, size_t ws_size,
                              hipStream_t stream) {
  const float* Q   = (const float*)d_in[0];
  const float* K   = (const float*)d_in[1];
  const float* V   = (const float*)d_in[2];
  const float* Qw  = (const float*)d_in[3];
  const float* Qb  = (const float*)d_in[4];
  const float* Kw  = (const float*)d_in[5];
  const float* Kb  = (const float*)d_in[6];
  const float* Vw  = (const float*)d_in[7];
  const float* Vb  = (const float*)d_in[8];
  const float* Pw  = (const float*)d_in[9];
  const float* Pb  = (const float*)d_in[10];
  const float* rpb = (const float*)d_in[11];
  const int*   rpi = (const int*)d_in[12];

  unsigned short* wbf = (unsigned short*)d_ws;                 // 4*65536 bf16
  float* biasT = (float*)(wbf + 4 * 65536);                    // 8*49*49 f32 (transposed)

  const size_t need = (size_t)4 * 65536 * 2 + (size_t)8 * NTOK * NTOK * 4;
  if (ws_size < need) return;  // loud failure signal (output stays poisoned)

  prep_kernel<<<1024, 256, 0, stream>>>(Qw, Kw, Vw, Pw, rpb, rpi, wbf, biasT);
  fused_kernel<<<NWIN, 512, 0, stream>>>(Q, K, V, Qb, Kb, Vb, Pb, wbf, biasT,
                                         (float*)d_out);
}